// Round 1
// baseline (529.720 us; speedup 1.0000x reference)
//
#include <hip/hip_runtime.h>
#include <hip/hip_bf16.h>

typedef short bf16x8 __attribute__((ext_vector_type(8)));
typedef float f32x4 __attribute__((ext_vector_type(4)));

#define CCH 512
#define NPIX 4096
#define NB 4

__device__ inline unsigned short f2bf(float f) {
  union { __hip_bfloat16 h; unsigned short u; } cv;
  cv.h = __float2bfloat16(f);
  return cv.u;
}

// ---------------- weight fp32 -> bf16 cast ----------------
__global__ __launch_bounds__(256) void cast_weights_k(
    const float* __restrict__ w0, const float* __restrict__ w1,
    const float* __restrict__ w2, const float* __restrict__ w3,
    unsigned short* __restrict__ out) {
  int z = blockIdx.y;
  const float* src = (z == 0) ? w0 : (z == 1) ? w1 : (z == 2) ? w2 : w3;
  long i = (long)blockIdx.x * 256 + threadIdx.x;
  out[(long)z * CCH * CCH + i] = f2bf(src[i]);
}

// ---------------- instance-norm stats: one block per (b,c) plane ----------------
__global__ __launch_bounds__(256) void stats_k(const float* __restrict__ x,
                                               float* __restrict__ stats) {
  long plane = blockIdx.x;
  const float4* p = (const float4*)(x + plane * NPIX);
  int t = threadIdx.x;
  float s = 0.f, q = 0.f;
  for (int c = 0; c < 4; c++) {
    float4 v = p[c * 256 + t];
    s += v.x + v.y + v.z + v.w;
    q += v.x * v.x + v.y * v.y + v.z * v.z + v.w * v.w;
  }
  for (int off = 32; off; off >>= 1) { s += __shfl_xor(s, off); q += __shfl_xor(q, off); }
  __shared__ float rs[4], rq[4];
  int w = t >> 6;
  if ((t & 63) == 0) { rs[w] = s; rq[w] = q; }
  __syncthreads();
  if (t == 0) {
    s = rs[0] + rs[1] + rs[2] + rs[3];
    q = rq[0] + rq[1] + rq[2] + rq[3];
    float mu = s * (1.f / NPIX);
    float var = q * (1.f / NPIX) - mu * mu;
    stats[2 * plane] = mu;
    stats[2 * plane + 1] = rsqrtf(var + 1e-5f);
  }
}

// ---------------- normalize + transpose: x[b][c][i] -> hnT[b][i][c] bf16 ----------------
__global__ __launch_bounds__(256) void norm_t_k(const float* __restrict__ x,
                                                const float* __restrict__ stats,
                                                unsigned short* __restrict__ hnT) {
  int b = blockIdx.z;
  int c0 = blockIdx.y * 32, i0 = blockIdx.x * 32;
  __shared__ float tile[32][33];
  int t = threadIdx.x;
  int il = t & 31, cl = t >> 5;  // cl in 0..7
  for (int r = 0; r < 4; r++) {
    int c = c0 + cl + r * 8;
    long pl = (long)b * CCH + c;
    float mu = stats[2 * pl], rsg = stats[2 * pl + 1];
    tile[cl + r * 8][il] = (x[pl * NPIX + i0 + il] - mu) * rsg;
  }
  __syncthreads();
  for (int r = 0; r < 4; r++) {
    int i = i0 + cl + r * 8;
    hnT[((long)b * NPIX + i) * CCH + c0 + il] = f2bf(tile[il][cl + r * 8]);
  }
}

// ---------------- generic bf16 gemm_bt: C[m][n] = A[m][k] * B[n][k] ----------------
// 128x128 tile, BK=32, 4 waves (2x2), 4x4 16x16x32 mfma frags per wave.
// OUTF32: 1 -> float C, 0 -> bf16 C. BIASM: 0 none, 1 bias[m], 2 bias[n].
template <int OUTF32, int BIASM, bool RESID, bool SCALE>
__global__ __launch_bounds__(256) void gemm_bt_k(
    const unsigned short* __restrict__ A, const unsigned short* __restrict__ B,
    void* __restrict__ Cv, const float* __restrict__ bias,
    const float* __restrict__ resid, int K, int lda, int ldb, int ldc,
    long sA, long sB, long sC, float scale) {
  int z = blockIdx.z;
  A += z * sA;
  B += z * sB;
  const int n0 = blockIdx.x * 128, m0 = blockIdx.y * 128;
  const int t = threadIdx.x;
  const int lane = t & 63, w = t >> 6;
  const int wr = w >> 1, wc = w & 1;

  __shared__ unsigned short As[128 * 32];
  __shared__ unsigned short Bs[128 * 32];

  f32x4 acc[4][4] = {};

  const int r0 = t >> 2;            // 0..63
  const int uk = (t & 3) * 8;       // k-element offset within 32
  const unsigned short* pa0 = A + (long)(m0 + r0) * lda + uk;
  const unsigned short* pa1 = A + (long)(m0 + 64 + r0) * lda + uk;
  const unsigned short* pb0 = B + (long)(n0 + r0) * ldb + uk;
  const unsigned short* pb1 = B + (long)(n0 + 64 + r0) * ldb + uk;

  bf16x8 va0 = *(const bf16x8*)(pa0);
  bf16x8 va1 = *(const bf16x8*)(pa1);
  bf16x8 vb0 = *(const bf16x8*)(pb0);
  bf16x8 vb1 = *(const bf16x8*)(pb1);

  unsigned short* wA0 = As + r0 * 32 + uk;
  unsigned short* wA1 = As + (64 + r0) * 32 + uk;
  unsigned short* wB0 = Bs + r0 * 32 + uk;
  unsigned short* wB1 = Bs + (64 + r0) * 32 + uk;

  const int fr = lane & 15, fk = (lane >> 4) * 8;
  const unsigned short* rA = As + (wr * 64 + fr) * 32 + fk;
  const unsigned short* rB = Bs + (wc * 64 + fr) * 32 + fk;

  const int nkt = K >> 5;
  for (int kt = 0; kt < nkt; kt++) {
    *(bf16x8*)wA0 = va0;
    *(bf16x8*)wA1 = va1;
    *(bf16x8*)wB0 = vb0;
    *(bf16x8*)wB1 = vb1;
    __syncthreads();
    if (kt + 1 < nkt) {  // prefetch next k-tile while mfma runs
      int ko = (kt + 1) << 5;
      va0 = *(const bf16x8*)(pa0 + ko);
      va1 = *(const bf16x8*)(pa1 + ko);
      vb0 = *(const bf16x8*)(pb0 + ko);
      vb1 = *(const bf16x8*)(pb1 + ko);
    }
    bf16x8 af[4], bfr[4];
    for (int i = 0; i < 4; i++) af[i] = *(const bf16x8*)(rA + i * 16 * 32);
    for (int i = 0; i < 4; i++) bfr[i] = *(const bf16x8*)(rB + i * 16 * 32);
    for (int i = 0; i < 4; i++)
      for (int j = 0; j < 4; j++)
        acc[i][j] = __builtin_amdgcn_mfma_f32_16x16x32_bf16(af[i], bfr[j], acc[i][j], 0, 0, 0);
    __syncthreads();
  }

  // epilogue: C/D layout col = lane&15, row = (lane>>4)*4 + r  (m89-verified)
  const int fq = lane >> 4;
  float* Cf = (float*)Cv;
  unsigned short* Cb = (unsigned short*)Cv;
  for (int i = 0; i < 4; i++) {
    int mg = m0 + wr * 64 + i * 16 + fq * 4;
    for (int j = 0; j < 4; j++) {
      int ng = n0 + wc * 64 + j * 16 + fr;
      for (int r = 0; r < 4; r++) {
        float v = acc[i][j][r];
        if (SCALE) v *= scale;
        int m = mg + r;
        if (BIASM == 1) v += bias[m];
        else if (BIASM == 2) v += bias[ng];
        long off = z * sC + (long)m * ldc + ng;
        if (OUTF32) {
          if (RESID) v += resid[off];
          Cf[off] = v;
        } else {
          Cb[off] = f2bf(v);
        }
      }
    }
  }
}

// ---------------- row softmax: S (f32, 4096 cols) -> P (bf16, normalized) ----------------
__global__ __launch_bounds__(256) void softmax_k(const float* __restrict__ S,
                                                 unsigned short* __restrict__ P) {
  long r = blockIdx.x;
  const float4* row = (const float4*)(S + r * NPIX);
  int t = threadIdx.x;
  float4 v[4];
  float m = -1e30f;
  for (int c = 0; c < 4; c++) {
    v[c] = row[c * 256 + t];
    m = fmaxf(m, fmaxf(fmaxf(v[c].x, v[c].y), fmaxf(v[c].z, v[c].w)));
  }
  for (int off = 32; off; off >>= 1) m = fmaxf(m, __shfl_xor(m, off));
  __shared__ float red[4], red2[4];
  int w = t >> 6;
  if ((t & 63) == 0) red[w] = m;
  __syncthreads();
  m = fmaxf(fmaxf(red[0], red[1]), fmaxf(red[2], red[3]));
  float s = 0.f;
  float4 e[4];
  for (int c = 0; c < 4; c++) {
    e[c].x = __expf(v[c].x - m);
    e[c].y = __expf(v[c].y - m);
    e[c].z = __expf(v[c].z - m);
    e[c].w = __expf(v[c].w - m);
    s += e[c].x + e[c].y + e[c].z + e[c].w;
  }
  for (int off = 32; off; off >>= 1) s += __shfl_xor(s, off);
  if ((t & 63) == 0) red2[w] = s;
  __syncthreads();
  s = red2[0] + red2[1] + red2[2] + red2[3];
  float inv = 1.f / s;
  ushort4* Pp = (ushort4*)(P + r * NPIX);
  for (int c = 0; c < 4; c++) {
    ushort4 u;
    u.x = f2bf(e[c].x * inv);
    u.y = f2bf(e[c].y * inv);
    u.z = f2bf(e[c].z * inv);
    u.w = f2bf(e[c].w * inv);
    Pp[c * 256 + t] = u;
  }
}

extern "C" void kernel_launch(void* const* d_in, const int* in_sizes, int n_in,
                              void* d_out, int out_size, void* d_ws, size_t ws_size,
                              hipStream_t stream) {
  const float* x  = (const float*)d_in[0];
  const float* wq = (const float*)d_in[1];
  const float* bq = (const float*)d_in[2];
  const float* wk = (const float*)d_in[3];
  const float* bk = (const float*)d_in[4];
  const float* wv = (const float*)d_in[5];
  const float* bv = (const float*)d_in[6];
  const float* wp = (const float*)d_in[7];
  const float* bp = (const float*)d_in[8];

  char* ws = (char*)d_ws;
  const long SLAB = (long)NPIX * CCH;  // 2,097,152 elements per (batch) slab
  float* stats = (float*)ws;                                     // 16 KB
  unsigned short* wbf = (unsigned short*)(ws + (1l << 16));      // 2 MB
  unsigned short* hnT = (unsigned short*)(ws + (1l << 16) + (1l << 21));
  unsigned short* Qt = hnT + 4 * SLAB;   // [b][i][o] bf16, 16 MB
  unsigned short* Kt = Qt + 4 * SLAB;    // [b][j][o]
  unsigned short* V  = Kt + 4 * SLAB;    // [b][o][j]
  unsigned short* Ot = V + 4 * SLAB;     // [b][i][c]
  unsigned short* P  = Ot + 4 * SLAB;    // [i][j] bf16, 32 MB (per-batch reuse)
  float* S = (float*)(P + (long)NPIX * NPIX);  // [i][j] f32, 64 MB (per-batch reuse)

  unsigned short* wq_bf = wbf;
  unsigned short* wk_bf = wbf + 262144;
  unsigned short* wv_bf = wbf + 2 * 262144;
  unsigned short* wp_bf = wbf + 3 * 262144;

  cast_weights_k<<<dim3(1024, 4, 1), 256, 0, stream>>>(wq, wk, wv, wp, wbf);
  stats_k<<<dim3(NB * CCH, 1, 1), 256, 0, stream>>>(x, stats);
  norm_t_k<<<dim3(128, 16, 4), 256, 0, stream>>>(x, stats, hnT);

  // Qt[i][o] = hnT . Wq^T + bq (bias over cols)
  gemm_bt_k<0, 2, false, false><<<dim3(4, 32, 4), 256, 0, stream>>>(
      hnT, wq_bf, Qt, bq, nullptr, 512, 512, 512, 512, SLAB, 0, SLAB, 1.f);
  gemm_bt_k<0, 2, false, false><<<dim3(4, 32, 4), 256, 0, stream>>>(
      hnT, wk_bf, Kt, bk, nullptr, 512, 512, 512, 512, SLAB, 0, SLAB, 1.f);
  // V[o][j] = Wv . hnT^T + bv (bias over rows)
  gemm_bt_k<0, 1, false, false><<<dim3(32, 4, 4), 256, 0, stream>>>(
      wv_bf, hnT, V, bv, nullptr, 512, 512, 512, 4096, 0, SLAB, SLAB, 1.f);

  const float isc = 0.044194173824159216f;  // 1/sqrt(512)
  for (int b = 0; b < 4; b++) {
    // S[i][j] = Qt . Kt^T / sqrt(C)
    gemm_bt_k<1, 0, false, true><<<dim3(32, 32, 1), 256, 0, stream>>>(
        Qt + b * SLAB, Kt + b * SLAB, S, nullptr, nullptr, 512, 512, 512, 4096,
        0, 0, 0, isc);
    softmax_k<<<dim3(NPIX, 1, 1), 256, 0, stream>>>(S, P);
    // Ot[i][c] = P . V^T
    gemm_bt_k<0, 0, false, false><<<dim3(4, 32, 1), 256, 0, stream>>>(
        P, V + b * SLAB, Ot + b * SLAB, nullptr, nullptr, 4096, 4096, 4096, 512,
        0, 0, 0, 1.f);
  }
  // out[o][i] = x + Wp . Ot^T + bp
  gemm_bt_k<1, 1, true, false><<<dim3(32, 4, 4), 256, 0, stream>>>(
      wp_bf, Ot, d_out, bp, x, 512, 512, 512, 4096, 0, SLAB, SLAB, 1.f);
}

// Round 3
// 445.094 us; speedup vs baseline: 1.1901x; 1.1901x over previous
//
#include <hip/hip_runtime.h>
#include <hip/hip_bf16.h>

typedef short bf16x8 __attribute__((ext_vector_type(8)));
typedef float f32x4 __attribute__((ext_vector_type(4)));

#define CCH 512
#define NPIX 4096
#define NB 4

__device__ inline unsigned short f2bf(float f) {
  union { __hip_bfloat16 h; unsigned short u; } cv;
  cv.h = __float2bfloat16(f);
  return cv.u;
}

#define GLD16(gp, lp) __builtin_amdgcn_global_load_lds( \
    (const __attribute__((address_space(1))) unsigned int*)(gp), \
    (__attribute__((address_space(3))) unsigned int*)(lp), 16, 0, 0)

// ---------------- weight fp32 -> bf16 cast ----------------
__global__ __launch_bounds__(256) void cast_weights_k(
    const float* __restrict__ w0, const float* __restrict__ w1,
    const float* __restrict__ w2, const float* __restrict__ w3,
    unsigned short* __restrict__ out) {
  int z = blockIdx.y;
  const float* src = (z == 0) ? w0 : (z == 1) ? w1 : (z == 2) ? w2 : w3;
  long i = (long)blockIdx.x * 256 + threadIdx.x;
  out[(long)z * CCH * CCH + i] = f2bf(src[i]);
}

// ---------------- instance-norm stats: one block per (b,c) plane ----------------
__global__ __launch_bounds__(256) void stats_k(const float* __restrict__ x,
                                               float* __restrict__ stats) {
  long plane = blockIdx.x;
  const float4* p = (const float4*)(x + plane * NPIX);
  int t = threadIdx.x;
  float s = 0.f, q = 0.f;
  for (int c = 0; c < 4; c++) {
    float4 v = p[c * 256 + t];
    s += v.x + v.y + v.z + v.w;
    q += v.x * v.x + v.y * v.y + v.z * v.z + v.w * v.w;
  }
  for (int off = 32; off; off >>= 1) { s += __shfl_xor(s, off); q += __shfl_xor(q, off); }
  __shared__ float rs[4], rq[4];
  int w = t >> 6;
  if ((t & 63) == 0) { rs[w] = s; rq[w] = q; }
  __syncthreads();
  if (t == 0) {
    s = rs[0] + rs[1] + rs[2] + rs[3];
    q = rq[0] + rq[1] + rq[2] + rq[3];
    float mu = s * (1.f / NPIX);
    float var = q * (1.f / NPIX) - mu * mu;
    stats[2 * plane] = mu;
    stats[2 * plane + 1] = rsqrtf(var + 1e-5f);
  }
}

// ---------------- normalize + transpose: x[b][c][i] -> hnT[b][i][c] bf16 ----------------
__global__ __launch_bounds__(256) void norm_t_k(const float* __restrict__ x,
                                                const float* __restrict__ stats,
                                                unsigned short* __restrict__ hnT) {
  int b = blockIdx.z;
  int c0 = blockIdx.y * 32, i0 = blockIdx.x * 32;
  __shared__ float tile[32][33];
  int t = threadIdx.x;
  int il = t & 31, cl = t >> 5;  // cl in 0..7
  for (int r = 0; r < 4; r++) {
    int c = c0 + cl + r * 8;
    long pl = (long)b * CCH + c;
    float mu = stats[2 * pl], rsg = stats[2 * pl + 1];
    tile[cl + r * 8][il] = (x[pl * NPIX + i0 + il] - mu) * rsg;
  }
  __syncthreads();
  for (int r = 0; r < 4; r++) {
    int i = i0 + cl + r * 8;
    hnT[((long)b * NPIX + i) * CCH + c0 + il] = f2bf(tile[il][cl + r * 8]);
  }
}

// ---------------- generic bf16 gemm_bt: C[m][n] = A[m][k] * B[n][k] ----------------
// m97 structure: 128x128 tile, BK=64, global_load_lds dwordx4 staging,
// 4 waves (2x2), 4x4 16x16x32 mfma frags per wave.
// OUTF32: 1 -> float C, 0 -> bf16 C. BIASM: 0 none, 1 bias[m], 2 bias[n].
// SPLITK: blockIdx.z = k-slice (K/4 each), C offset z*sC; else z = batch.
template <int OUTF32, int BIASM, bool RESID, bool SCALE, bool SPLITK>
__global__ __launch_bounds__(256) void gemm_bt_k(
    const unsigned short* __restrict__ A, const unsigned short* __restrict__ B,
    void* __restrict__ Cv, const float* __restrict__ bias,
    const float* __restrict__ resid, int K, int lda, int ldb, int ldc,
    long sA, long sB, long sC, float scale) {
  int z = blockIdx.z;
  int kbeg = 0, kend = K >> 6;
  if (SPLITK) {
    int kq = (K >> 6) >> 2;
    kbeg = z * kq;
    kend = kbeg + kq;
  } else {
    A += z * sA;
    B += z * sB;
  }
  const int n0 = blockIdx.x * 128, m0 = blockIdx.y * 128;
  const int t = threadIdx.x;
  const int lane = t & 63, w = t >> 6;
  const int wr = w >> 1, wc = w & 1;

  __shared__ __align__(16) unsigned short As[128 * 64];  // 16 KB, linear [row][64]
  __shared__ __align__(16) unsigned short Bs[128 * 64];  // 16 KB

  f32x4 acc[4][4] = {};

  // staging: chunk j (j=0..3) covers rows j*32 + (t>>3), elem col (t&7)*8
  // LDS byte dest for chunk j = j*4096 + t*16  (linear in t -> valid gload_lds dest)
  const int srow = t >> 3;       // 0..31
  const int scol = (t & 7) * 8;  // element offset within BK=64
  const unsigned short* ga = A + (long)(m0 + srow) * lda + scol;
  const unsigned short* gb = B + (long)(n0 + srow) * ldb + scol;
  char* lA = (char*)As + t * 16;
  char* lB = (char*)Bs + t * 16;
  const long stpa = (long)32 * lda;
  const long stpb = (long)32 * ldb;

  const int fr = lane & 15, fk = (lane >> 4) * 8;
  const unsigned short* rA = As + (wr * 64 + fr) * 64 + fk;
  const unsigned short* rB = Bs + (wc * 64 + fr) * 64 + fk;

  for (int kt = kbeg; kt < kend; kt++) {
    const unsigned short* gak = ga + kt * 64;
    const unsigned short* gbk = gb + kt * 64;
    GLD16(gak, lA);
    GLD16(gak + stpa, lA + 4096);
    GLD16(gak + 2 * stpa, lA + 8192);
    GLD16(gak + 3 * stpa, lA + 12288);
    GLD16(gbk, lB);
    GLD16(gbk + stpb, lB + 4096);
    GLD16(gbk + 2 * stpb, lB + 8192);
    GLD16(gbk + 3 * stpb, lB + 12288);
    __syncthreads();
    for (int kk = 0; kk < 2; kk++) {
      bf16x8 af[4], bfr[4];
      for (int i = 0; i < 4; i++) af[i] = *(const bf16x8*)(rA + i * 16 * 64 + kk * 32);
      for (int i = 0; i < 4; i++) bfr[i] = *(const bf16x8*)(rB + i * 16 * 64 + kk * 32);
      for (int i = 0; i < 4; i++)
        for (int j = 0; j < 4; j++)
          acc[i][j] = __builtin_amdgcn_mfma_f32_16x16x32_bf16(af[i], bfr[j], acc[i][j], 0, 0, 0);
    }
    __syncthreads();
  }

  // epilogue: C/D layout col = lane&15, row = (lane>>4)*4 + r  (m89-verified)
  const int fq = lane >> 4;
  float* Cf = (float*)Cv;
  unsigned short* Cb = (unsigned short*)Cv;
  for (int i = 0; i < 4; i++) {
    int mg = m0 + wr * 64 + i * 16 + fq * 4;
    for (int j = 0; j < 4; j++) {
      int ng = n0 + wc * 64 + j * 16 + fr;
      for (int r = 0; r < 4; r++) {
        float v = acc[i][j][r];
        if (SCALE) v *= scale;
        int m = mg + r;
        if (BIASM == 1) v += bias[m];
        else if (BIASM == 2) v += bias[ng];
        long off = z * sC + (long)m * ldc + ng;
        if (OUTF32) {
          if (RESID) v += resid[off];
          Cf[off] = v;
        } else {
          Cb[off] = f2bf(v);
        }
      }
    }
  }
}

// ---------------- sum 4 fp32 split-k partials -> bf16 ----------------
__global__ __launch_bounds__(256) void reduce4_k(const float* __restrict__ part,
                                                 unsigned short* __restrict__ out) {
  const long S4 = (long)NPIX * CCH;  // 2M elements per partial
  long i = ((long)blockIdx.x * 256 + threadIdx.x) * 4;
  float4 a = *(const float4*)(part + i);
  float4 b = *(const float4*)(part + S4 + i);
  float4 c = *(const float4*)(part + 2 * S4 + i);
  float4 d = *(const float4*)(part + 3 * S4 + i);
  ushort4 u;
  u.x = f2bf(a.x + b.x + c.x + d.x);
  u.y = f2bf(a.y + b.y + c.y + d.y);
  u.z = f2bf(a.z + b.z + c.z + d.z);
  u.w = f2bf(a.w + b.w + c.w + d.w);
  *(ushort4*)(out + i) = u;
}

// ---------------- row softmax: S (f32, 4096 cols) -> P (bf16, normalized) ----------------
__global__ __launch_bounds__(256) void softmax_k(const float* __restrict__ S,
                                                 unsigned short* __restrict__ P) {
  long r = blockIdx.x;
  const float4* row = (const float4*)(S + r * NPIX);
  int t = threadIdx.x;
  float4 v[4];
  float m = -1e30f;
  for (int c = 0; c < 4; c++) {
    v[c] = row[c * 256 + t];
    m = fmaxf(m, fmaxf(fmaxf(v[c].x, v[c].y), fmaxf(v[c].z, v[c].w)));
  }
  for (int off = 32; off; off >>= 1) m = fmaxf(m, __shfl_xor(m, off));
  __shared__ float red[4], red2[4];
  int w = t >> 6;
  if ((t & 63) == 0) red[w] = m;
  __syncthreads();
  m = fmaxf(fmaxf(red[0], red[1]), fmaxf(red[2], red[3]));
  float s = 0.f;
  float4 e[4];
  for (int c = 0; c < 4; c++) {
    e[c].x = __expf(v[c].x - m);
    e[c].y = __expf(v[c].y - m);
    e[c].z = __expf(v[c].z - m);
    e[c].w = __expf(v[c].w - m);
    s += e[c].x + e[c].y + e[c].z + e[c].w;
  }
  for (int off = 32; off; off >>= 1) s += __shfl_xor(s, off);
  if ((t & 63) == 0) red2[w] = s;
  __syncthreads();
  s = red2[0] + red2[1] + red2[2] + red2[3];
  float inv = 1.f / s;
  ushort4* Pp = (ushort4*)(P + r * NPIX);
  for (int c = 0; c < 4; c++) {
    ushort4 u;
    u.x = f2bf(e[c].x * inv);
    u.y = f2bf(e[c].y * inv);
    u.z = f2bf(e[c].z * inv);
    u.w = f2bf(e[c].w * inv);
    Pp[c * 256 + t] = u;
  }
}

extern "C" void kernel_launch(void* const* d_in, const int* in_sizes, int n_in,
                              void* d_out, int out_size, void* d_ws, size_t ws_size,
                              hipStream_t stream) {
  const float* x  = (const float*)d_in[0];
  const float* wq = (const float*)d_in[1];
  const float* bq = (const float*)d_in[2];
  const float* wk = (const float*)d_in[3];
  const float* bk = (const float*)d_in[4];
  const float* wv = (const float*)d_in[5];
  const float* bv = (const float*)d_in[6];
  const float* wp = (const float*)d_in[7];
  const float* bp = (const float*)d_in[8];

  char* ws = (char*)d_ws;
  const long SLAB = (long)NPIX * CCH;  // 2,097,152 elements per batch slab
  float* stats = (float*)ws;                                     // 16 KB
  unsigned short* wbf = (unsigned short*)(ws + (1l << 16));      // 2 MB
  unsigned short* hnT = (unsigned short*)(ws + (1l << 16) + (1l << 21));
  unsigned short* Qt = hnT + 4 * SLAB;   // [b][i][o] bf16, 16 MB
  unsigned short* Kt = Qt + 4 * SLAB;    // [b][j][o]
  unsigned short* V  = Kt + 4 * SLAB;    // [b][o][j]
  unsigned short* Ot = V + 4 * SLAB;     // [b][i][c]
  float* S = (float*)(Ot + 4 * SLAB);    // [i][j] f32, 64 MB (per-batch reuse;
                                         //  also reused as 4x8MB split-k partials)
  unsigned short* P = (unsigned short*)(S + (long)NPIX * NPIX);  // 32 MB, per-batch

  unsigned short* wq_bf = wbf;
  unsigned short* wk_bf = wbf + 262144;
  unsigned short* wv_bf = wbf + 2 * 262144;
  unsigned short* wp_bf = wbf + 3 * 262144;

  cast_weights_k<<<dim3(1024, 4, 1), 256, 0, stream>>>(wq, wk, wv, wp, wbf);
  stats_k<<<dim3(NB * CCH, 1, 1), 256, 0, stream>>>(x, stats);
  norm_t_k<<<dim3(128, 16, 4), 256, 0, stream>>>(x, stats, hnT);

  // Qt[i][o] = hnT . Wq^T + bq (bias over cols)
  gemm_bt_k<0, 2, false, false, false><<<dim3(4, 32, 4), 256, 0, stream>>>(
      hnT, wq_bf, Qt, bq, nullptr, 512, 512, 512, 512, SLAB, 0, SLAB, 1.f);
  gemm_bt_k<0, 2, false, false, false><<<dim3(4, 32, 4), 256, 0, stream>>>(
      hnT, wk_bf, Kt, bk, nullptr, 512, 512, 512, 512, SLAB, 0, SLAB, 1.f);
  // V[o][j] = Wv . hnT^T + bv (bias over rows)
  gemm_bt_k<0, 1, false, false, false><<<dim3(32, 4, 4), 256, 0, stream>>>(
      wv_bf, hnT, V, bv, nullptr, 512, 512, 512, 4096, 0, SLAB, SLAB, 1.f);

  const float isc = 0.044194173824159216f;  // 1/sqrt(512)
  for (int b = 0; b < 4; b++) {
    // S[i][j] = Qt . Kt^T / sqrt(C)
    gemm_bt_k<1, 0, false, true, false><<<dim3(32, 32, 1), 256, 0, stream>>>(
        Qt + b * SLAB, Kt + b * SLAB, S, nullptr, nullptr, 512, 512, 512, 4096,
        0, 0, 0, isc);
    softmax_k<<<dim3(NPIX, 1, 1), 256, 0, stream>>>(S, P);
    // S is dead now; reuse its region for split-k fp32 partials (4 x 8 MB).
    // Opart[z][i][c] = P[:, z-slice] . V[:, z-slice]^T
    gemm_bt_k<1, 0, false, false, true><<<dim3(4, 32, 4), 256, 0, stream>>>(
        P, V + b * SLAB, S, nullptr, nullptr, 4096, 4096, 4096, 512,
        0, 0, SLAB, 1.f);
    reduce4_k<<<dim3(2048, 1, 1), 256, 0, stream>>>(S, Ot + b * SLAB);
  }
  // out[o][i] = x + Wp . Ot^T + bp
  gemm_bt_k<1, 1, true, false, false><<<dim3(32, 4, 4), 256, 0, stream>>>(
      wp_bf, Ot, d_out, bp, x, 512, 512, 512, 4096, 0, SLAB, SLAB, 1.f);
}

// Round 4
// 358.951 us; speedup vs baseline: 1.4757x; 1.2400x over previous
//
#include <hip/hip_runtime.h>
#include <hip/hip_bf16.h>

typedef short bf16x8 __attribute__((ext_vector_type(8)));
typedef unsigned short u16x8 __attribute__((ext_vector_type(8)));
typedef float f32x4 __attribute__((ext_vector_type(4)));

#define CCH 512
#define NPIX 4096
#define NB 4

__device__ inline unsigned short f2bf(float f) {
  union { __hip_bfloat16 h; unsigned short u; } cv;
  cv.h = __float2bfloat16(f);
  return cv.u;
}
__device__ inline float bf2f(unsigned short u) {
  union { float f; unsigned int i; } c;
  c.i = ((unsigned int)u) << 16;
  return c.f;
}

#define GLD16(gp, lp) __builtin_amdgcn_global_load_lds( \
    (const __attribute__((address_space(1))) unsigned int*)(gp), \
    (__attribute__((address_space(3))) unsigned int*)(lp), 16, 0, 0)

// ---------------- weight fp32 -> bf16 cast ----------------
__global__ __launch_bounds__(256) void cast_weights_k(
    const float* __restrict__ w0, const float* __restrict__ w1,
    const float* __restrict__ w2, const float* __restrict__ w3,
    unsigned short* __restrict__ out) {
  int z = blockIdx.y;
  const float* src = (z == 0) ? w0 : (z == 1) ? w1 : (z == 2) ? w2 : w3;
  long i = (long)blockIdx.x * 256 + threadIdx.x;
  out[(long)z * CCH * CCH + i] = f2bf(src[i]);
}

// ---------------- concat bq,bk -> bqk[1024] ----------------
__global__ __launch_bounds__(256) void bias_concat_k(
    const float* __restrict__ bq, const float* __restrict__ bk,
    float* __restrict__ bqk) {
  int i = blockIdx.x * 256 + threadIdx.x;
  bqk[i] = (i < CCH) ? bq[i] : bk[i - CCH];
}

// ---------------- instance-norm stats: one block per (b,c) plane ----------------
__global__ __launch_bounds__(256) void stats_k(const float* __restrict__ x,
                                               float* __restrict__ stats) {
  long plane = blockIdx.x;
  const float4* p = (const float4*)(x + plane * NPIX);
  int t = threadIdx.x;
  float s = 0.f, q = 0.f;
  for (int c = 0; c < 4; c++) {
    float4 v = p[c * 256 + t];
    s += v.x + v.y + v.z + v.w;
    q += v.x * v.x + v.y * v.y + v.z * v.z + v.w * v.w;
  }
  for (int off = 32; off; off >>= 1) { s += __shfl_xor(s, off); q += __shfl_xor(q, off); }
  __shared__ float rs[4], rq[4];
  int w = t >> 6;
  if ((t & 63) == 0) { rs[w] = s; rq[w] = q; }
  __syncthreads();
  if (t == 0) {
    s = rs[0] + rs[1] + rs[2] + rs[3];
    q = rq[0] + rq[1] + rq[2] + rq[3];
    float mu = s * (1.f / NPIX);
    float var = q * (1.f / NPIX) - mu * mu;
    stats[2 * plane] = mu;
    stats[2 * plane + 1] = rsqrtf(var + 1e-5f);
  }
}

// ---------------- normalize + transpose: x[b][c][i] -> hnT[b][i][c] bf16 ----------------
__global__ __launch_bounds__(256) void norm_t_k(const float* __restrict__ x,
                                                const float* __restrict__ stats,
                                                unsigned short* __restrict__ hnT) {
  int b = blockIdx.z;
  int c0 = blockIdx.y * 32, i0 = blockIdx.x * 32;
  __shared__ float tile[32][33];
  int t = threadIdx.x;
  int il = t & 31, cl = t >> 5;  // cl in 0..7
  for (int r = 0; r < 4; r++) {
    int c = c0 + cl + r * 8;
    long pl = (long)b * CCH + c;
    float mu = stats[2 * pl], rsg = stats[2 * pl + 1];
    tile[cl + r * 8][il] = (x[pl * NPIX + i0 + il] - mu) * rsg;
  }
  __syncthreads();
  for (int r = 0; r < 4; r++) {
    int i = i0 + cl + r * 8;
    hnT[((long)b * NPIX + i) * CCH + c0 + il] = f2bf(tile[il][cl + r * 8]);
  }
}

// ---------------- generic bf16 gemm_bt: C[m][n] = A[m][k] * B[n][k] ----------------
// m97 structure: 128x128 tile, BK=64, global_load_lds dwordx4 staging,
// 4 waves (2x2), 4x4 16x16x32 mfma frags per wave.
// OUTF32: 1 -> float C, 0 -> bf16 C. BIASM: 0 none, 1 bias[m], 2 bias[n].
template <int OUTF32, int BIASM, bool RESID, bool SCALE>
__global__ __launch_bounds__(256) void gemm_bt_k(
    const unsigned short* __restrict__ A, const unsigned short* __restrict__ B,
    void* __restrict__ Cv, const float* __restrict__ bias,
    const float* __restrict__ resid, int K, int lda, int ldb, int ldc,
    long sA, long sB, long sC, float scale) {
  int z = blockIdx.z;
  A += z * sA;
  B += z * sB;
  const int n0 = blockIdx.x * 128, m0 = blockIdx.y * 128;
  const int t = threadIdx.x;
  const int lane = t & 63, w = t >> 6;
  const int wr = w >> 1, wc = w & 1;

  __shared__ __align__(16) unsigned short As[128 * 64];  // 16 KB, linear [row][64]
  __shared__ __align__(16) unsigned short Bs[128 * 64];  // 16 KB

  f32x4 acc[4][4] = {};

  // staging: chunk j (j=0..3) covers rows j*32 + (t>>3), elem col (t&7)*8
  // LDS byte dest for chunk j = j*4096 + t*16  (linear in t -> valid gload_lds dest)
  const int srow = t >> 3;       // 0..31
  const int scol = (t & 7) * 8;  // element offset within BK=64
  const unsigned short* ga = A + (long)(m0 + srow) * lda + scol;
  const unsigned short* gb = B + (long)(n0 + srow) * ldb + scol;
  char* lA = (char*)As + t * 16;
  char* lB = (char*)Bs + t * 16;
  const long stpa = (long)32 * lda;
  const long stpb = (long)32 * ldb;

  const int fr = lane & 15, fk = (lane >> 4) * 8;
  const unsigned short* rA = As + (wr * 64 + fr) * 64 + fk;
  const unsigned short* rB = Bs + (wc * 64 + fr) * 64 + fk;

  const int nkt = K >> 6;
  for (int kt = 0; kt < nkt; kt++) {
    const unsigned short* gak = ga + kt * 64;
    const unsigned short* gbk = gb + kt * 64;
    GLD16(gak, lA);
    GLD16(gak + stpa, lA + 4096);
    GLD16(gak + 2 * stpa, lA + 8192);
    GLD16(gak + 3 * stpa, lA + 12288);
    GLD16(gbk, lB);
    GLD16(gbk + stpb, lB + 4096);
    GLD16(gbk + 2 * stpb, lB + 8192);
    GLD16(gbk + 3 * stpb, lB + 12288);
    __syncthreads();
    for (int kk = 0; kk < 2; kk++) {
      bf16x8 af[4], bfr[4];
      for (int i = 0; i < 4; i++) af[i] = *(const bf16x8*)(rA + i * 16 * 64 + kk * 32);
      for (int i = 0; i < 4; i++) bfr[i] = *(const bf16x8*)(rB + i * 16 * 64 + kk * 32);
      for (int i = 0; i < 4; i++)
        for (int j = 0; j < 4; j++)
          acc[i][j] = __builtin_amdgcn_mfma_f32_16x16x32_bf16(af[i], bfr[j], acc[i][j], 0, 0, 0);
    }
    __syncthreads();
  }

  // epilogue: C/D layout col = lane&15, row = (lane>>4)*4 + r  (m89-verified)
  const int fq = lane >> 4;
  float* Cf = (float*)Cv;
  unsigned short* Cb = (unsigned short*)Cv;
  for (int i = 0; i < 4; i++) {
    int mg = m0 + wr * 64 + i * 16 + fq * 4;
    for (int j = 0; j < 4; j++) {
      int ng = n0 + wc * 64 + j * 16 + fr;
      for (int r = 0; r < 4; r++) {
        float v = acc[i][j][r];
        if (SCALE) v *= scale;
        int m = mg + r;
        if (BIASM == 1) v += bias[m];
        else if (BIASM == 2) v += bias[ng];
        long off = z * sC + (long)m * ldc + ng;
        if (OUTF32) {
          if (RESID) v += resid[off];
          Cf[off] = v;
        } else {
          Cb[off] = f2bf(v);
        }
      }
    }
  }
}

// ---------------- in-place row softmax on bf16 S (4096 cols) ----------------
__global__ __launch_bounds__(256) void softmax_bf16_k(unsigned short* __restrict__ S) {
  long base = (long)blockIdx.y * NPIX * NPIX + (long)blockIdx.x * NPIX;
  unsigned short* row = S + base;
  int t = threadIdx.x;
  u16x8 a = *(const u16x8*)(row + t * 16);
  u16x8 b = *(const u16x8*)(row + t * 16 + 8);
  float v[16];
  float m = -1e30f;
  for (int i = 0; i < 8; i++) { v[i] = bf2f(a[i]); v[8 + i] = bf2f(b[i]); }
  for (int i = 0; i < 16; i++) m = fmaxf(m, v[i]);
  for (int off = 32; off; off >>= 1) m = fmaxf(m, __shfl_xor(m, off));
  __shared__ float red[4], red2[4];
  int w = t >> 6;
  if ((t & 63) == 0) red[w] = m;
  __syncthreads();
  m = fmaxf(fmaxf(red[0], red[1]), fmaxf(red[2], red[3]));
  float s = 0.f;
  for (int i = 0; i < 16; i++) { v[i] = __expf(v[i] - m); s += v[i]; }
  for (int off = 32; off; off >>= 1) s += __shfl_xor(s, off);
  if ((t & 63) == 0) red2[w] = s;
  __syncthreads();
  s = red2[0] + red2[1] + red2[2] + red2[3];
  float inv = 1.f / s;
  u16x8 oa, ob;
  for (int i = 0; i < 8; i++) {
    oa[i] = f2bf(v[i] * inv);
    ob[i] = f2bf(v[8 + i] * inv);
  }
  *(u16x8*)(row + t * 16) = oa;
  *(u16x8*)(row + t * 16 + 8) = ob;
}

extern "C" void kernel_launch(void* const* d_in, const int* in_sizes, int n_in,
                              void* d_out, int out_size, void* d_ws, size_t ws_size,
                              hipStream_t stream) {
  const float* x  = (const float*)d_in[0];
  const float* wq = (const float*)d_in[1];
  const float* bq = (const float*)d_in[2];
  const float* wk = (const float*)d_in[3];
  const float* bk = (const float*)d_in[4];
  const float* wv = (const float*)d_in[5];
  const float* bv = (const float*)d_in[6];
  const float* wp = (const float*)d_in[7];
  const float* bp = (const float*)d_in[8];

  char* ws = (char*)d_ws;
  const long SLAB = (long)NPIX * CCH;     // 2M elems: one batch of hnT/V/Ot
  const long SLAB2 = (long)NPIX * 1024;   // 4M elems: one batch of QKt
  const long SLABP = (long)NPIX * NPIX;   // 16.8M elems: one batch of S/P

  float* stats = (float*)ws;                                // 16 KB
  float* bqk = (float*)(ws + (32l << 10));                  // 4 KB
  unsigned short* wbf = (unsigned short*)(ws + (64l << 10));  // 2 MB
  unsigned short* hnT = (unsigned short*)(ws + (64l << 10) + (1l << 21));
  unsigned short* QKt = hnT + 4 * SLAB;   // [b][i][0:512 Q | 512:1024 K], 32 MB
  unsigned short* V   = QKt + 4 * SLAB2;  // [b][o][j], 16 MB
  unsigned short* Ot  = V + 4 * SLAB;     // [b][i][c], 16 MB
  unsigned short* S4  = Ot + 4 * SLAB;    // [b][i][j] bf16, 128 MB (S then P in-place)
  // total: ~210 MB

  unsigned short* wv_bf = wbf + 2 * 262144;
  unsigned short* wp_bf = wbf + 3 * 262144;

  cast_weights_k<<<dim3(1024, 4, 1), 256, 0, stream>>>(wq, wk, wv, wp, wbf);
  bias_concat_k<<<dim3(4, 1, 1), 256, 0, stream>>>(bq, bk, bqk);
  stats_k<<<dim3(NB * CCH, 1, 1), 256, 0, stream>>>(x, stats);
  norm_t_k<<<dim3(128, 16, 4), 256, 0, stream>>>(x, stats, hnT);

  // QKt[b][i][n] = hnT[b] . [wq;wk]^T + bqk   (n in 0..1023)
  gemm_bt_k<0, 2, false, false><<<dim3(8, 32, 4), 256, 0, stream>>>(
      hnT, wbf, QKt, bqk, nullptr, 512, 512, 512, 1024, SLAB, 0, SLAB2, 1.f);
  // V[b][o][j] = Wv . hnT[b]^T + bv (bias over rows)
  gemm_bt_k<0, 1, false, false><<<dim3(32, 4, 4), 256, 0, stream>>>(
      wv_bf, hnT, V, bv, nullptr, 512, 512, 512, 4096, 0, SLAB, SLAB, 1.f);

  const float isc = 0.044194173824159216f;  // 1/sqrt(512)
  // S[b][i][j] = Q[b] . K[b]^T / sqrt(C), stored bf16
  gemm_bt_k<0, 0, false, true><<<dim3(32, 32, 4), 256, 0, stream>>>(
      QKt, QKt + 512, S4, nullptr, nullptr, 512, 1024, 1024, 4096,
      SLAB2, SLAB2, SLABP, isc);
  // in-place softmax: S -> P (bf16)
  softmax_bf16_k<<<dim3(NPIX, NB, 1), 256, 0, stream>>>(S4);
  // Ot[b][i][c] = P[b] . V[b]^T
  gemm_bt_k<0, 0, false, false><<<dim3(4, 32, 4), 256, 0, stream>>>(
      S4, V, Ot, nullptr, nullptr, 4096, 4096, 4096, 512, SLABP, SLAB, SLAB, 1.f);
  // out[b][o][i] = x + Wp . Ot[b]^T + bp
  gemm_bt_k<1, 1, true, false><<<dim3(32, 4, 4), 256, 0, stream>>>(
      wp_bf, Ot, d_out, bp, x, 512, 512, 512, 4096, 0, SLAB, SLAB, 1.f);
}